// Round 3
// baseline (400.492 us; speedup 1.0000x reference)
//
#include <hip/hip_runtime.h>
#include <hip/hip_bf16.h>

#define NS 65536
#define NQ 131072
#define DD 256
#define NC 1024
#define BM 32

typedef __attribute__((ext_vector_type(8))) short short8;
typedef __attribute__((ext_vector_type(4))) float f32x4;

// LDS carve (bytes). 4 B-stage buffers of 32 KB; A above them; misc on top.
// Epilogue reuses bytes [0,131072) as a [32][1024] f32 output image.
#define STGSZ      32768
#define SMEM_A     131072
#define SMEM_QI    147456
#define SMEM_RED   147584
#define SMEM_ROWM  148608
#define SMEM_ROWL  148736
#define SMEM_TOTAL 148864

static __device__ __forceinline__ unsigned short f2bf(float f) {
    unsigned int u = __float_as_uint(f);
    u += 0x7fffu + ((u >> 16) & 1u);          // round-to-nearest-even
    return (unsigned short)(u >> 16);
}

static __device__ __forceinline__ void gload_lds16(const void* src, void* dst) {
    using GPtr = const __attribute__((address_space(1))) unsigned int*;
    using LPtr = __attribute__((address_space(3))) unsigned int*;
    GPtr g = reinterpret_cast<GPtr>(reinterpret_cast<uintptr_t>(src));
    LPtr l = reinterpret_cast<LPtr>(static_cast<unsigned int>(reinterpret_cast<uintptr_t>(dst)));
    __builtin_amdgcn_global_load_lds(g, l, 16, 0, 0);
}

// K1a: per-row inverse L2 norm of support rows (one wave per row)
__global__ __launch_bounds__(256) void k_rinv(const float* __restrict__ sf,
                                              float* __restrict__ rinv) {
    const int row  = (blockIdx.x << 2) + (threadIdx.x >> 6);
    const int lane = threadIdx.x & 63;
    float4 v = *reinterpret_cast<const float4*>(sf + (size_t)row * DD + lane * 4);
    float ss = v.x*v.x + v.y*v.y + v.z*v.z + v.w*v.w;
#pragma unroll
    for (int off = 32; off; off >>= 1) ss += __shfl_xor(ss, off);
    if (lane == 0) rinv[row] = 1.0f / fmaxf(sqrtf(ss), 1e-8f);
}

// K1b: one block per class, ballot-compacted row list, no global atomics.
__global__ __launch_bounds__(256) void k_proto(const float* __restrict__ sf,
                                               const int* __restrict__ labels,
                                               const float* __restrict__ rinv,
                                               unsigned short* __restrict__ pb,
                                               float* __restrict__ outTail) {
    __shared__ int lists[4][96];
    __shared__ int wcnts[4];
    __shared__ float red[4];
    const int c = blockIdx.x;
    const int t = threadIdx.x;
    const int w = t >> 6;
    const int lane = t & 63;

    int cnt = 0;
    const int base0 = w * (NS / 4);
#pragma unroll 4
    for (int i = 0; i < NS / 4; i += 64) {
        const int lab = labels[base0 + i + lane];
        const unsigned long long m = __ballot(lab == c);
        if (lab == c) {
            int pos = cnt + __popcll(m & ((1ull << lane) - 1ull));
            if (pos < 96) lists[w][pos] = base0 + i + lane;
        }
        cnt += (int)__popcll(m);
    }
    if (lane == 0) wcnts[w] = cnt;
    __syncthreads();

    float acc = 0.f;
    int total = 0;
    for (int ww = 0; ww < 4; ++ww) {
        const int n = min(wcnts[ww], 96);
        total += wcnts[ww];
        for (int j = 0; j < n; ++j) {
            const int row = lists[ww][j];
            acc += sf[(size_t)row * DD + t] * rinv[row];
        }
    }
    const float m = acc / fmaxf((float)total, 1.0f);
    float ss = m * m;
#pragma unroll
    for (int off = 32; off; off >>= 1) ss += __shfl_xor(ss, off);
    if ((t & 63) == 0) red[t >> 6] = ss;
    __syncthreads();
    const float tot = red[0] + red[1] + red[2] + red[3];
    const float r = 1.0f / fmaxf(sqrtf(tot), 1e-8f);
    pb[(size_t)c * DD + t] = f2bf(m * r);
    if (t == 0) outTail[c] = (float)c;
}

// stage one 32 KB half-tile: stage s -> cols (s&7)*128..+128, dims (s>>3)*128..+128
// LDS dest linear; global source pre-swizzled (involution with the ds_read XOR).
static __device__ __forceinline__ void stageHalf(char* smem, const char* pbB,
                                                 int w, int lane, int stage, char* bufBase) {
    const int ct = stage & 7;
    const int kh = stage >> 3;
#pragma unroll
    for (int i = 0; i < 4; ++i) {
        const int e   = w * 256 + i * 64 + lane;   // 16B-chunk index 0..2047
        const int col = e >> 4;                     // within-tile col 0..127
        const int c16 = e & 15;                     // chunk within 256B col-row
        const char* src = pbB + ((size_t)(ct * 128 + col) << 9) + (kh << 8)
                              + ((c16 ^ (col & 7)) << 4);
        char* dst = bufBase + w * 4096 + i * 1024;  // wave-uniform; HW adds lane*16
        gload_lds16(src, dst);
    }
}

// K3: fused GEMM + qnorm + log_softmax. 512 thr = 8 waves, BM=32 rows/block.
// 16 stages, 4 LDS buffers, counted vmcnt(8), setprio around MFMA.
__global__ __launch_bounds__(512, 2) void k_gemm_lsm(const float* __restrict__ qf,
                                                     const unsigned short* __restrict__ pb,
                                                     float* __restrict__ out) {
    extern __shared__ char smem[];
    const int tid  = threadIdx.x;
    const int w    = tid >> 6;
    const int lane = tid & 63;
    const int g    = lane >> 4;
    const int r16  = lane & 15;
    const size_t qbase = (size_t)blockIdx.x * BM;
    const char* pbB = (const char*)pb;

    // prologue: issue 3 stages, then A-stage
    stageHalf(smem, pbB, w, lane, 0, smem);
    stageHalf(smem, pbB, w, lane, 1, smem + STGSZ);
    stageHalf(smem, pbB, w, lane, 2, smem + 2 * STGSZ);

    {
        const int row = tid >> 4;
        const int seg = tid & 15;
        const float* qrow = qf + (qbase + row) * (size_t)DD + seg * 16;
        float4 f0 = *reinterpret_cast<const float4*>(qrow + 0);
        float4 f1 = *reinterpret_cast<const float4*>(qrow + 4);
        float4 f2 = *reinterpret_cast<const float4*>(qrow + 8);
        float4 f3 = *reinterpret_cast<const float4*>(qrow + 12);
        float ss = f0.x*f0.x + f0.y*f0.y + f0.z*f0.z + f0.w*f0.w
                 + f1.x*f1.x + f1.y*f1.y + f1.z*f1.z + f1.w*f1.w
                 + f2.x*f2.x + f2.y*f2.y + f2.z*f2.z + f2.w*f2.w
                 + f3.x*f3.x + f3.y*f3.y + f3.z*f3.z + f3.w*f3.w;
        ss += __shfl_xor(ss, 1); ss += __shfl_xor(ss, 2);
        ss += __shfl_xor(ss, 4); ss += __shfl_xor(ss, 8);
        short8 h0, h1;
        h0[0]=(short)f2bf(f0.x); h0[1]=(short)f2bf(f0.y); h0[2]=(short)f2bf(f0.z); h0[3]=(short)f2bf(f0.w);
        h0[4]=(short)f2bf(f1.x); h0[5]=(short)f2bf(f1.y); h0[6]=(short)f2bf(f1.z); h0[7]=(short)f2bf(f1.w);
        h1[0]=(short)f2bf(f2.x); h1[1]=(short)f2bf(f2.y); h1[2]=(short)f2bf(f2.z); h1[3]=(short)f2bf(f2.w);
        h1[4]=(short)f2bf(f3.x); h1[5]=(short)f2bf(f3.y); h1[6]=(short)f2bf(f3.z); h1[7]=(short)f2bf(f3.w);
        const int x = row & 7;
        char* aRow = smem + SMEM_A + row * 512;
        *reinterpret_cast<short8*>(aRow + (((seg*2)     ^ x) << 4)) = h0;
        *reinterpret_cast<short8*>(aRow + (((seg*2 + 1) ^ x) << 4)) = h1;
        if (seg == 0)
            reinterpret_cast<float*>(smem + SMEM_QI)[row] = 1.0f / fmaxf(sqrtf(ss), 1e-8f);
    }
    __syncthreads();   // one-time full drain: stages 0-2 + A in LDS

    // hoist A frags: 64 VGPRs, reused across all stages
    short8 a[2][8];
#pragma unroll
    for (int m2 = 0; m2 < 2; ++m2)
#pragma unroll
        for (int kk = 0; kk < 8; ++kk) {
            const int row = m2 * 16 + r16;
            const int chunk = (kk * 4 + g) ^ (row & 7);
            a[m2][kk] = *reinterpret_cast<const short8*>(smem + SMEM_A + row * 512 + chunk * 16);
        }

    f32x4 acc[2][8];
#pragma unroll
    for (int m2 = 0; m2 < 2; ++m2)
#pragma unroll
        for (int n = 0; n < 8; ++n) acc[m2][n] = (f32x4){0.f, 0.f, 0.f, 0.f};

    const int colL = w * 16 + r16;
    const int bswz = colL & 7;

    // main pipeline: stage t+3 in flight; never drain vmcnt to 0
#pragma unroll
    for (int t = 0; t < 16; ++t) {
        asm volatile("s_waitcnt vmcnt(8)" ::: "memory");
        __builtin_amdgcn_s_barrier();
        if (t + 3 < 16)
            stageHalf(smem, pbB, w, lane, t + 3, smem + ((t + 3) & 3) * STGSZ);
        const char* bBase = smem + (t & 3) * STGSZ + colL * 256;
        const int ct = t & 7;
        const int kh = t >> 3;
        __builtin_amdgcn_s_setprio(1);
#pragma unroll
        for (int kk = 0; kk < 4; ++kk) {
            short8 b = *reinterpret_cast<const short8*>(bBase + (((kk * 4 + g) ^ bswz) << 4));
            acc[0][ct] = __builtin_amdgcn_mfma_f32_16x16x32_bf16(a[0][kh * 4 + kk], b, acc[0][ct], 0, 0, 0);
            acc[1][ct] = __builtin_amdgcn_mfma_f32_16x16x32_bf16(a[1][kh * 4 + kk], b, acc[1][ct], 0, 0, 0);
        }
        __builtin_amdgcn_s_setprio(0);
    }
    __syncthreads();   // all B reads done; B buffers become the f32 out image

    // ---- epilogue: qinv scale + row log_softmax ----
    float* qinvLds = reinterpret_cast<float*>(smem + SMEM_QI);
    float (*red)[8] = reinterpret_cast<float(*)[8]>(smem + SMEM_RED);
    float* rowM = reinterpret_cast<float*>(smem + SMEM_ROWM);
    float* rowL = reinterpret_cast<float*>(smem + SMEM_ROWL);

    float qi[2][4];
#pragma unroll
    for (int m2 = 0; m2 < 2; ++m2)
#pragma unroll
        for (int j = 0; j < 4; ++j) qi[m2][j] = qinvLds[m2 * 16 + g * 4 + j];

#pragma unroll
    for (int m2 = 0; m2 < 2; ++m2)
#pragma unroll
        for (int n = 0; n < 8; ++n)
#pragma unroll
            for (int j = 0; j < 4; ++j) acc[m2][n][j] *= qi[m2][j];

    float rmax[2][4];
#pragma unroll
    for (int m2 = 0; m2 < 2; ++m2)
#pragma unroll
        for (int j = 0; j < 4; ++j) {
            float v = acc[m2][0][j];
#pragma unroll
            for (int n = 1; n < 8; ++n) v = fmaxf(v, acc[m2][n][j]);
#pragma unroll
            for (int off = 1; off < 16; off <<= 1) v = fmaxf(v, __shfl_xor(v, off));
            rmax[m2][j] = v;
        }
    if (r16 == 0) {
#pragma unroll
        for (int m2 = 0; m2 < 2; ++m2)
#pragma unroll
            for (int j = 0; j < 4; ++j) red[m2 * 16 + g * 4 + j][w] = rmax[m2][j];
    }
    __syncthreads();
    if (tid < 32) {
        float v = red[tid][0];
#pragma unroll
        for (int k = 1; k < 8; ++k) v = fmaxf(v, red[tid][k]);
        rowM[tid] = v;
    }
    __syncthreads();

    float rsum[2][4];
#pragma unroll
    for (int m2 = 0; m2 < 2; ++m2)
#pragma unroll
        for (int j = 0; j < 4; ++j) {
            const float rm = rowM[m2 * 16 + g * 4 + j];
            float s = 0.f;
#pragma unroll
            for (int n = 0; n < 8; ++n) s += __expf(acc[m2][n][j] - rm);
#pragma unroll
            for (int off = 1; off < 16; off <<= 1) s += __shfl_xor(s, off);
            rsum[m2][j] = s;
        }
    if (r16 == 0) {
#pragma unroll
        for (int m2 = 0; m2 < 2; ++m2)
#pragma unroll
            for (int j = 0; j < 4; ++j) red[m2 * 16 + g * 4 + j][w] = rsum[m2][j];
    }
    __syncthreads();
    if (tid < 32) {
        float s = red[tid][0];
#pragma unroll
        for (int k = 1; k < 8; ++k) s += red[tid][k];
        rowL[tid] = rowM[tid] + __logf(s);
    }
    __syncthreads();

    // write final values into the [32][1024] f32 LDS image
#pragma unroll
    for (int m2 = 0; m2 < 2; ++m2)
#pragma unroll
        for (int j = 0; j < 4; ++j) {
            const float sub = rowL[m2 * 16 + g * 4 + j];
            float* lrow = reinterpret_cast<float*>(smem) + (m2 * 16 + g * 4 + j) * NC;
#pragma unroll
            for (int n = 0; n < 8; ++n)
                lrow[n * 128 + w * 16 + r16] = acc[m2][n][j] - sub;
        }
    __syncthreads();

    // coalesced dwordx4 store: thread t owns row t>>4, chunks (t&15)+16s
    {
        const int orow = tid >> 4;
        const int rr = tid & 15;
        float* gout = out + (qbase + orow) * (size_t)NC;
#pragma unroll
        for (int s = 0; s < 16; ++s) {
            f32x4 v = *reinterpret_cast<const f32x4*>(smem + orow * 4096 + (s * 16 + rr) * 16);
            *reinterpret_cast<f32x4*>(gout + (s * 16 + rr) * 4) = v;
        }
    }
}

extern "C" void kernel_launch(void* const* d_in, const int* in_sizes, int n_in,
                              void* d_out, int out_size, void* d_ws, size_t ws_size,
                              hipStream_t stream) {
    const float* sf     = (const float*)d_in[0];
    const int*   labels = (const int*)d_in[1];
    const float* qf     = (const float*)d_in[2];
    float* out = (float*)d_out;

    float* rinv = (float*)d_ws;                                          // 256 KiB
    unsigned short* pb = (unsigned short*)((char*)d_ws + (size_t)NS * 4); // 512 KiB

    hipFuncSetAttribute(reinterpret_cast<const void*>(k_gemm_lsm),
                        hipFuncAttributeMaxDynamicSharedMemorySize, SMEM_TOTAL);

    k_rinv<<<NS / 4, 256, 0, stream>>>(sf, rinv);

    float* outTail = out + (size_t)out_size - NC;
    k_proto<<<NC, 256, 0, stream>>>(sf, labels, rinv, pb, outTail);

    k_gemm_lsm<<<NQ / BM, 512, SMEM_TOTAL, stream>>>(qf, pb, out);
}

// Round 4
// 330.767 us; speedup vs baseline: 1.2108x; 1.2108x over previous
//
#include <hip/hip_runtime.h>
#include <hip/hip_bf16.h>

#define NS 65536
#define NQ 131072
#define DD 256
#define NC 1024
#define BM 32
#define LCAP 128

typedef __attribute__((ext_vector_type(8))) short short8;
typedef __attribute__((ext_vector_type(4))) float f32x4;

// LDS carve (bytes): per-wave private B double-buffers [8 waves][2][8192],
// then A, then misc. Epilogue reuses [0,131072) as [32][1024] f32 image.
#define SMEM_A     131072
#define SMEM_QI    147456
#define SMEM_RED   147584
#define SMEM_ROWM  148608
#define SMEM_ROWL  148736
#define SMEM_TOTAL 148864

static __device__ __forceinline__ unsigned short f2bf(float f) {
    unsigned int u = __float_as_uint(f);
    u += 0x7fffu + ((u >> 16) & 1u);          // round-to-nearest-even
    return (unsigned short)(u >> 16);
}

static __device__ __forceinline__ void gload_lds16(const void* src, void* dst) {
    using GPtr = const __attribute__((address_space(1))) unsigned int*;
    using LPtr = __attribute__((address_space(3))) unsigned int*;
    GPtr g = reinterpret_cast<GPtr>(reinterpret_cast<uintptr_t>(src));
    LPtr l = reinterpret_cast<LPtr>(static_cast<unsigned int>(reinterpret_cast<uintptr_t>(dst)));
    __builtin_amdgcn_global_load_lds(g, l, 16, 0, 0);
}

// K1: one sf pass: per-row rinv (wave per row) + per-class compact row list
// via one int atomicAdd per row. No label scans anywhere.
__global__ __launch_bounds__(256) void k_count(const float* __restrict__ sf,
                                               const int* __restrict__ labels,
                                               float* __restrict__ rinv,
                                               int* __restrict__ cnts,
                                               int* __restrict__ lists) {
    const int row  = (blockIdx.x << 2) + (threadIdx.x >> 6);
    const int lane = threadIdx.x & 63;
    float4 v = *reinterpret_cast<const float4*>(sf + (size_t)row * DD + lane * 4);
    float ss = v.x*v.x + v.y*v.y + v.z*v.z + v.w*v.w;
#pragma unroll
    for (int off = 32; off; off >>= 1) ss += __shfl_xor(ss, off);
    if (lane == 0) {
        rinv[row] = 1.0f / fmaxf(sqrtf(ss), 1e-8f);
        const int lab = labels[row];
        const int slot = atomicAdd(&cnts[lab], 1);
        if (slot < LCAP) lists[lab * LCAP + slot] = row;
    }
}

// K2: block per class, gather listed rows, mean -> l2norm -> bf16 + arange tail.
__global__ __launch_bounds__(256) void k_proto(const float* __restrict__ sf,
                                               const float* __restrict__ rinv,
                                               const int* __restrict__ cnts,
                                               const int* __restrict__ lists,
                                               unsigned short* __restrict__ pb,
                                               float* __restrict__ outTail) {
    __shared__ float red[4];
    const int c = blockIdx.x;
    const int t = threadIdx.x;
    const int total = cnts[c];
    const int n = min(total, LCAP);
    float acc = 0.f;
    for (int j = 0; j < n; ++j) {
        const int row = lists[c * LCAP + j];
        acc += sf[(size_t)row * DD + t] * rinv[row];
    }
    const float m = acc / fmaxf((float)total, 1.0f);
    float ss = m * m;
#pragma unroll
    for (int off = 32; off; off >>= 1) ss += __shfl_xor(ss, off);
    if ((t & 63) == 0) red[t >> 6] = ss;
    __syncthreads();
    const float tot = red[0] + red[1] + red[2] + red[3];
    const float r = 1.0f / fmaxf(sqrtf(tot), 1e-8f);
    pb[(size_t)c * DD + t] = f2bf(m * r);
    if (t == 0) outTail[c] = (float)c;
}

// stage this wave's 16-col x 256-dim slice of tile t (8 KB) into its private buf.
// Global source pre-swizzled (chunk c stored at LDS chunk c ^ ((col&7)<<1)).
static __device__ __forceinline__ void stageW(char* myBuf, const char* colBase, int lane) {
#pragma unroll
    for (int i = 0; i < 8; ++i) {
        const int e   = i * 64 + lane;          // 16B-chunk idx within [16 col][32 chunk]
        const int col = e >> 5;
        const int c   = e & 31;
        const char* src = colBase + ((size_t)col << 9) + ((c ^ ((col & 7) << 1)) << 4);
        gload_lds16(src, myBuf + i * 1024);     // wave-uniform dst; HW adds lane*16
    }
}

// K3: fused GEMM + qnorm + log_softmax. 512 thr = 8 waves, BM=32 rows/block.
// Barrier-FREE K-loop: each wave owns a disjoint 16-col B slice per tile,
// staged into its private LDS double-buffer; per-wave vmcnt pipelining.
__global__ __launch_bounds__(512, 2) void k_gemm_lsm(const float* __restrict__ qf,
                                                     const unsigned short* __restrict__ pb,
                                                     float* __restrict__ out) {
    extern __shared__ char smem[];
    const int tid  = threadIdx.x;
    const int w    = tid >> 6;
    const int lane = tid & 63;
    const int g    = lane >> 4;
    const int r16  = lane & 15;
    const size_t qbase = (size_t)blockIdx.x * BM;
    const char* pbB = (const char*)pb;
    char* myB = smem + w * 16384;               // [2][8192] private to wave w

    // prologue: issue tile-0 stage, then cooperative A-stage
    stageW(myB, pbB + ((size_t)(w * 16) << 9), lane);
    {
        const int row = tid >> 4;
        const int seg = tid & 15;
        const float* qrow = qf + (qbase + row) * (size_t)DD + seg * 16;
        float4 f0 = *reinterpret_cast<const float4*>(qrow + 0);
        float4 f1 = *reinterpret_cast<const float4*>(qrow + 4);
        float4 f2 = *reinterpret_cast<const float4*>(qrow + 8);
        float4 f3 = *reinterpret_cast<const float4*>(qrow + 12);
        float ss = f0.x*f0.x + f0.y*f0.y + f0.z*f0.z + f0.w*f0.w
                 + f1.x*f1.x + f1.y*f1.y + f1.z*f1.z + f1.w*f1.w
                 + f2.x*f2.x + f2.y*f2.y + f2.z*f2.z + f2.w*f2.w
                 + f3.x*f3.x + f3.y*f3.y + f3.z*f3.z + f3.w*f3.w;
        ss += __shfl_xor(ss, 1); ss += __shfl_xor(ss, 2);
        ss += __shfl_xor(ss, 4); ss += __shfl_xor(ss, 8);
        short8 h0, h1;
        h0[0]=(short)f2bf(f0.x); h0[1]=(short)f2bf(f0.y); h0[2]=(short)f2bf(f0.z); h0[3]=(short)f2bf(f0.w);
        h0[4]=(short)f2bf(f1.x); h0[5]=(short)f2bf(f1.y); h0[6]=(short)f2bf(f1.z); h0[7]=(short)f2bf(f1.w);
        h1[0]=(short)f2bf(f2.x); h1[1]=(short)f2bf(f2.y); h1[2]=(short)f2bf(f2.z); h1[3]=(short)f2bf(f2.w);
        h1[4]=(short)f2bf(f3.x); h1[5]=(short)f2bf(f3.y); h1[6]=(short)f2bf(f3.z); h1[7]=(short)f2bf(f3.w);
        const int x = row & 7;
        char* aRow = smem + SMEM_A + row * 512;
        *reinterpret_cast<short8*>(aRow + (((seg*2)     ^ x) << 4)) = h0;
        *reinterpret_cast<short8*>(aRow + (((seg*2 + 1) ^ x) << 4)) = h1;
        if (seg == 0)
            reinterpret_cast<float*>(smem + SMEM_QI)[row] = 1.0f / fmaxf(sqrtf(ss), 1e-8f);
    }
    __syncthreads();   // one-time full drain: tile0 B + A in LDS

    // hoist A frags: 64 VGPRs, reused across all tiles
    short8 a[2][8];
#pragma unroll
    for (int m2 = 0; m2 < 2; ++m2)
#pragma unroll
        for (int kk = 0; kk < 8; ++kk) {
            const int row = m2 * 16 + r16;
            const int chunk = (kk * 4 + g) ^ (row & 7);
            a[m2][kk] = *reinterpret_cast<const short8*>(smem + SMEM_A + row * 512 + chunk * 16);
        }

    f32x4 acc[2][8];
#pragma unroll
    for (int m2 = 0; m2 < 2; ++m2)
#pragma unroll
        for (int n = 0; n < 8; ++n) acc[m2][n] = (f32x4){0.f, 0.f, 0.f, 0.f};

    const int bswz = (r16 & 7) << 1;

    // barrier-free per-wave pipeline over 8 col-tiles
#pragma unroll
    for (int t = 0; t < 8; ++t) {
        if (t < 7) {
            stageW(myB + (((t + 1) & 1) << 13),
                   pbB + ((size_t)((t + 1) * 128 + w * 16) << 9), lane);
            asm volatile("s_waitcnt vmcnt(8)" ::: "memory");   // tile t's 8 loads done
        } else {
            asm volatile("s_waitcnt vmcnt(0)" ::: "memory");
        }
        const char* bB = myB + ((t & 1) << 13) + r16 * 512;
        __builtin_amdgcn_s_setprio(1);
#pragma unroll
        for (int kk = 0; kk < 8; ++kk) {
            short8 b = *reinterpret_cast<const short8*>(bB + (((kk * 4 + g) ^ bswz) << 4));
            acc[0][t] = __builtin_amdgcn_mfma_f32_16x16x32_bf16(a[0][kk], b, acc[0][t], 0, 0, 0);
            acc[1][t] = __builtin_amdgcn_mfma_f32_16x16x32_bf16(a[1][kk], b, acc[1][t], 0, 0, 0);
        }
        __builtin_amdgcn_s_setprio(0);
    }
    __syncthreads();   // all waves done; B region becomes the f32 out image

    // ---- epilogue: qinv scale + row log_softmax ----
    float* qinvLds = reinterpret_cast<float*>(smem + SMEM_QI);
    float (*red)[8] = reinterpret_cast<float(*)[8]>(smem + SMEM_RED);
    float* rowM = reinterpret_cast<float*>(smem + SMEM_ROWM);
    float* rowL = reinterpret_cast<float*>(smem + SMEM_ROWL);

    float qi[2][4];
#pragma unroll
    for (int m2 = 0; m2 < 2; ++m2)
#pragma unroll
        for (int j = 0; j < 4; ++j) qi[m2][j] = qinvLds[m2 * 16 + g * 4 + j];

#pragma unroll
    for (int m2 = 0; m2 < 2; ++m2)
#pragma unroll
        for (int n = 0; n < 8; ++n)
#pragma unroll
            for (int j = 0; j < 4; ++j) acc[m2][n][j] *= qi[m2][j];

    float rmax[2][4];
#pragma unroll
    for (int m2 = 0; m2 < 2; ++m2)
#pragma unroll
        for (int j = 0; j < 4; ++j) {
            float v = acc[m2][0][j];
#pragma unroll
            for (int n = 1; n < 8; ++n) v = fmaxf(v, acc[m2][n][j]);
#pragma unroll
            for (int off = 1; off < 16; off <<= 1) v = fmaxf(v, __shfl_xor(v, off));
            rmax[m2][j] = v;
        }
    if (r16 == 0) {
#pragma unroll
        for (int m2 = 0; m2 < 2; ++m2)
#pragma unroll
            for (int j = 0; j < 4; ++j) red[m2 * 16 + g * 4 + j][w] = rmax[m2][j];
    }
    __syncthreads();
    if (tid < 32) {
        float v = red[tid][0];
#pragma unroll
        for (int k = 1; k < 8; ++k) v = fmaxf(v, red[tid][k]);
        rowM[tid] = v;
    }
    __syncthreads();

    float rsum[2][4];
#pragma unroll
    for (int m2 = 0; m2 < 2; ++m2)
#pragma unroll
        for (int j = 0; j < 4; ++j) {
            const float rm = rowM[m2 * 16 + g * 4 + j];
            float s = 0.f;
#pragma unroll
            for (int n = 0; n < 8; ++n) s += __expf(acc[m2][n][j] - rm);
#pragma unroll
            for (int off = 1; off < 16; off <<= 1) s += __shfl_xor(s, off);
            rsum[m2][j] = s;
        }
    if (r16 == 0) {
#pragma unroll
        for (int m2 = 0; m2 < 2; ++m2)
#pragma unroll
            for (int j = 0; j < 4; ++j) red[m2 * 16 + g * 4 + j][w] = rsum[m2][j];
    }
    __syncthreads();
    if (tid < 32) {
        float s = red[tid][0];
#pragma unroll
        for (int k = 1; k < 8; ++k) s += red[tid][k];
        rowL[tid] = rowM[tid] + __logf(s);
    }
    __syncthreads();

    // final values -> [32][1024] f32 LDS image
#pragma unroll
    for (int m2 = 0; m2 < 2; ++m2)
#pragma unroll
        for (int j = 0; j < 4; ++j) {
            const float sub = rowL[m2 * 16 + g * 4 + j];
            float* lrow = reinterpret_cast<float*>(smem) + (m2 * 16 + g * 4 + j) * NC;
#pragma unroll
            for (int n = 0; n < 8; ++n)
                lrow[n * 128 + w * 16 + r16] = acc[m2][n][j] - sub;
        }
    __syncthreads();

    // coalesced dwordx4 stores
    {
        const int orow = tid >> 4;
        const int rr = tid & 15;
        float* gout = out + (qbase + orow) * (size_t)NC;
#pragma unroll
        for (int s = 0; s < 16; ++s) {
            f32x4 v = *reinterpret_cast<const f32x4*>(smem + orow * 4096 + (s * 16 + rr) * 16);
            *reinterpret_cast<f32x4*>(gout + (s * 16 + rr) * 4) = v;
        }
    }
}

extern "C" void kernel_launch(void* const* d_in, const int* in_sizes, int n_in,
                              void* d_out, int out_size, void* d_ws, size_t ws_size,
                              hipStream_t stream) {
    const float* sf     = (const float*)d_in[0];
    const int*   labels = (const int*)d_in[1];
    const float* qf     = (const float*)d_in[2];
    float* out = (float*)d_out;

    char* ws = (char*)d_ws;
    float* rinv         = (float*)ws;                          // 256 KiB
    unsigned short* pb  = (unsigned short*)(ws + 262144);      // 512 KiB
    int* cnts           = (int*)(ws + 786432);                 // 4 KiB
    int* lists          = (int*)(ws + 790528);                 // 512 KiB

    hipFuncSetAttribute(reinterpret_cast<const void*>(k_gemm_lsm),
                        hipFuncAttributeMaxDynamicSharedMemorySize, SMEM_TOTAL);

    hipMemsetAsync(cnts, 0, NC * sizeof(int), stream);

    k_count<<<NS / 4, 256, 0, stream>>>(sf, labels, rinv, cnts, lists);

    float* outTail = out + (size_t)out_size - NC;
    k_proto<<<NC, 256, 0, stream>>>(sf, rinv, cnts, lists, pb, outTail);

    k_gemm_lsm<<<NQ / BM, 512, SMEM_TOTAL, stream>>>(qf, pb, out);
}